// Round 1
// baseline (347.445 us; speedup 1.0000x reference)
//
#include <hip/hip_runtime.h>
#include <math.h>

#define NB 32768
#define NT 48
#define NH 32
#define NOH 16
#define NK 3
#define NS 6
#define NSUB 4

typedef float f2 __attribute__((ext_vector_type(2)));

// Force a value/pair to stay live in VGPRs (compiler cannot rematerialize)
#define PIN_V(x) asm volatile("" : "+v"(x))
// Make a wave-uniform float SGPR-resident (legal VGPR->SGPR via readfirstlane)
__device__ __forceinline__ float uni(float x) {
    return __int_as_float(__builtin_amdgcn_readfirstlane(__float_as_int(x)));
}

// packed fma, src0 scalar-broadcast via op_sel (verified semantics in prior session):
//   LO: acc.{x,y} += zp.x * w.{x,y}      HI: acc.{x,y} += zp.y * w.{x,y}
#define PK_FMA_LO(acc, zp, w) \
    asm("v_pk_fma_f32 %0, %1, %2, %0 op_sel:[0,0,0] op_sel_hi:[0,1,1]" \
        : "+v"(acc) : "v"(zp), "v"(w))
#define PK_FMA_HI(acc, zp, w) \
    asm("v_pk_fma_f32 %0, %1, %2, %0 op_sel:[1,0,0] op_sel_hi:[1,1,1]" \
        : "+v"(acc) : "v"(zp), "v"(w))
// init forms: dst = bcast(zp)*w + c   (no accumulator-copy mov)
#define PK_FMA_LO_I(dst, zp, w, c) \
    asm("v_pk_fma_f32 %0, %1, %2, %3 op_sel:[0,0,0] op_sel_hi:[0,1,1]" \
        : "=v"(dst) : "v"(zp), "v"(w), "v"(c))
// swapped src0: lo-result uses zp.hi, hi-result uses zp.lo
#define PK_FMA_SWAP_I(dst, zp, cc, c) \
    asm("v_pk_fma_f32 %0, %1, %2, %3 op_sel:[1,0,0] op_sel_hi:[0,1,1]" \
        : "=v"(dst) : "v"(zp), "v"(cc), "v"(c))

__device__ __forceinline__ f2 fma2(f2 a, f2 b, f2 c) {
    return __builtin_elementwise_fma(a, b, c);
}
__device__ __forceinline__ f2 bc2(float x) { f2 r; r.x = x; r.y = x; return r; }

// partner-lane values via DPP quad_perm — full-rate VALU, stays inside the quad
__device__ __forceinline__ float dpp_xor1(float v) {   // quad_perm [1,0,3,2]
    int x = __builtin_amdgcn_update_dpp(0, __float_as_int(v), 0xB1, 0xF, 0xF, false);
    return __int_as_float(x);
}
__device__ __forceinline__ float dpp_xor2(float v) {   // quad_perm [2,3,0,1]
    int x = __builtin_amdgcn_update_dpp(0, __float_as_int(v), 0x4E, 0xF, 0xF, false);
    return __int_as_float(x);
}
__device__ __forceinline__ float dpp_xor3(float v) {   // quad_perm [3,2,1,0]
    int x = __builtin_amdgcn_update_dpp(0, __float_as_int(v), 0x1B, 0xF, 0xF, false);
    return __int_as_float(x);
}
// 4-lane butterfly sum: all 4 lanes of the quad end with the total (bitwise identical)
__device__ __forceinline__ float qsum4(float v) {
    float a = v + dpp_xor1(v);
    return a + dpp_xor2(a);
}

__device__ __forceinline__ float gelu_exact(float x) {
    return 0.5f * x * (1.0f + erff(x * 0.70710678118654752440f));
}

__global__ void __launch_bounds__(256, 2) pinod_kernel(
    const float* __restrict__ expr,
    const float* __restrict__ t_eval,
    const float* __restrict__ enc_w1,
    const float* __restrict__ enc_b1,
    const float* __restrict__ ln_g,
    const float* __restrict__ ln_b,
    const float* __restrict__ enc_w2,
    const float* __restrict__ enc_b2,
    const float* __restrict__ enc_w3,
    const float* __restrict__ enc_b3,
    const float* __restrict__ periods,
    const float* __restrict__ gammav,
    const float* __restrict__ ode_w1,
    const float* __restrict__ ode_b1,
    const float* __restrict__ ode_w2,
    const float* __restrict__ ode_b2,
    const float* __restrict__ dec_w,
    const float* __restrict__ dec_b,
    const float* __restrict__ baseline,
    float* __restrict__ out)
{
    const int tid   = blockIdx.x * 256 + threadIdx.x;
    const int sub   = tid & 3;          // lane within the element's quad
    const int b     = tid >> 2;         // element id
    const int base8 = sub * 8;          // encoder h-unit slice (8 of 32)
    const int obase = sub * 4;          // ODE hidden-unit slice (4 of 16)

    float* out_eh  = out;                                          // [NB][NT]
    float* out_tr  = out + (size_t)NB * NT;                        // [NT][NB][NS]
    float* out_amp = out + (size_t)NB * NT + (size_t)NT * NB * NS; // [NB][NK]

    const float C = 2.88539008177792681472f;   // 2*log2(e), folded into w1/b1

    // ======== ODE weights as f2 pairs, algebraically folded + pinned ========
    // w1p[i][p] = C * ode_w1[i][obase+2p .. +1]   (4 local hidden units -> 2 f2)
    f2 w1p[NS][2];
    #pragma unroll
    for (int i = 0; i < NS; ++i) {
        float4 wA = *(const float4*)(ode_w1 + i * NOH + obase);
        w1p[i][0].x = C * wA.x; w1p[i][0].y = C * wA.y;
        w1p[i][1].x = C * wA.z; w1p[i][1].y = C * wA.w;
    }
    f2 b1p[2];
    {
        float4 wA = *(const float4*)(ode_b1 + obase);
        b1p[0].x = C * wA.x; b1p[0].y = C * wA.y;
        b1p[1].x = C * wA.z; b1p[1].y = C * wA.w;
    }
    // y = 1 - 2*rc where rc = 1/(exp2(a')+1).  pd = sum_j y_j w2_j + b2
    //   = [0.25*b2 + sum_{local j} w2_j] + sum_{local j} rc_j * (-2 w2_j)
    //   (per-lane quarters of b2; totals assembled by the 2-stage butterfly)
    f2 w2p[4][3];      // -2 * ode_w2 rows (this lane's 4 hidden units)
    f2 hb2p[3];        // 0.25*b2 + sum of this lane's raw w2 rows
    #pragma unroll
    for (int s = 0; s < 3; ++s) {
        float2 w = *(const float2*)(ode_b2 + 2 * s);
        hb2p[s].x = 0.25f * w.x; hb2p[s].y = 0.25f * w.y;
    }
    #pragma unroll
    for (int j = 0; j < 4; ++j) {
        const float2* wp = (const float2*)(ode_w2 + (obase + j) * NS);
        #pragma unroll
        for (int s = 0; s < 3; ++s) {
            float2 w = wp[s];
            hb2p[s].x += w.x;          hb2p[s].y += w.y;
            w2p[j][s].x = -2.0f * w.x; w2p[j][s].y = -2.0f * w.y;
        }
    }
    // linear-dynamics constant pairs: d = (v, -om2*x - 2g*v) + pd
    f2 c1p[3], c2p[3];
    float dw[NK];
    #pragma unroll
    for (int k = 0; k < NK; ++k) {
        float w = 6.28318530717958647693f / uni(periods[k]);
        c1p[k].x = 1.0f; c1p[k].y = uni(-(w * w));
        c2p[k].x = 0.0f; c2p[k].y = uni(-2.0f * gammav[k]);
        dw[k]    = uni(dec_w[k]);
    }
    const float addc = uni(dec_b[0] + baseline[0]);

    #pragma unroll
    for (int i = 0; i < NS; ++i)
        #pragma unroll
        for (int p = 0; p < 2; ++p) PIN_V(w1p[i][p]);
    #pragma unroll
    for (int p = 0; p < 2; ++p) PIN_V(b1p[p]);
    #pragma unroll
    for (int j = 0; j < 4; ++j)
        #pragma unroll
        for (int s = 0; s < 3; ++s) PIN_V(w2p[j][s]);
    #pragma unroll
    for (int s = 0; s < 3; ++s) { PIN_V(hb2p[s]); PIN_V(c1p[s]); PIN_V(c2p[s]); }

    // ================= encoder (4-way split: 8 h-units per lane) ============
    float h1r[8];
    {
        float4 bv0 = *(const float4*)(enc_b1 + base8);
        float4 bv1 = *(const float4*)(enc_b1 + base8 + 4);
        h1r[0] = bv0.x; h1r[1] = bv0.y; h1r[2] = bv0.z; h1r[3] = bv0.w;
        h1r[4] = bv1.x; h1r[5] = bv1.y; h1r[6] = bv1.z; h1r[7] = bv1.w;
    }
    const float4* xp = (const float4*)(expr + (size_t)b * NT);
    #pragma unroll 1
    for (int t4 = 0; t4 < NT / 4; ++t4) {
        float4 xq = xp[t4];
        float xs[4] = {xq.x, xq.y, xq.z, xq.w};
        #pragma unroll
        for (int u4 = 0; u4 < 4; ++u4) {
            const float* wr = enc_w1 + (t4 * 4 + u4) * NH + base8;
            float x = xs[u4];
            float4 w0 = *(const float4*)(wr);
            float4 w1 = *(const float4*)(wr + 4);
            h1r[0] = fmaf(x, w0.x, h1r[0]); h1r[1] = fmaf(x, w0.y, h1r[1]);
            h1r[2] = fmaf(x, w0.z, h1r[2]); h1r[3] = fmaf(x, w0.w, h1r[3]);
            h1r[4] = fmaf(x, w1.x, h1r[4]); h1r[5] = fmaf(x, w1.y, h1r[5]);
            h1r[6] = fmaf(x, w1.z, h1r[6]); h1r[7] = fmaf(x, w1.w, h1r[7]);
        }
    }
    // layernorm across all 32 (2-stage butterfly) + gelu
    {
        float s = 0.f;
        #pragma unroll
        for (int u = 0; u < 8; ++u) s += h1r[u];
        float mu = qsum4(s) * (1.0f / NH);
        float v = 0.f;
        #pragma unroll
        for (int u = 0; u < 8; ++u) { float d = h1r[u] - mu; v = fmaf(d, d, v); }
        float var = qsum4(v) * (1.0f / NH);
        float rstd = rsqrtf(var + 1e-5f);
        float4 g0 = *(const float4*)(ln_g + base8);
        float4 g1 = *(const float4*)(ln_g + base8 + 4);
        float4 l0 = *(const float4*)(ln_b + base8);
        float4 l1 = *(const float4*)(ln_b + base8 + 4);
        h1r[0] = gelu_exact((h1r[0] - mu) * rstd * g0.x + l0.x);
        h1r[1] = gelu_exact((h1r[1] - mu) * rstd * g0.y + l0.y);
        h1r[2] = gelu_exact((h1r[2] - mu) * rstd * g0.z + l0.z);
        h1r[3] = gelu_exact((h1r[3] - mu) * rstd * g0.w + l0.w);
        h1r[4] = gelu_exact((h1r[4] - mu) * rstd * g1.x + l1.x);
        h1r[5] = gelu_exact((h1r[5] - mu) * rstd * g1.y + l1.y);
        h1r[6] = gelu_exact((h1r[6] - mu) * rstd * g1.z + l1.z);
        h1r[7] = gelu_exact((h1r[7] - mu) * rstd * g1.w + l1.w);
    }
    // h2 = gelu(h1 @ w2 + b2): lane owns j2 in [base8, base8+8)
    float acc[8];
    {
        float4 bv0 = *(const float4*)(enc_b2 + base8);
        float4 bv1 = *(const float4*)(enc_b2 + base8 + 4);
        acc[0] = bv0.x; acc[1] = bv0.y; acc[2] = bv0.z; acc[3] = bv0.w;
        acc[4] = bv1.x; acc[5] = bv1.y; acc[6] = bv1.z; acc[7] = bv1.w;
    }
    #pragma unroll 1
    for (int u = 0; u < 8; ++u) {
        float mine = h1r[u];                 // unit base8     + u
        float o1   = dpp_xor1(mine);         // unit (base8^8) + u
        float o2   = dpp_xor2(mine);         // unit (base8^16)+ u
        float o3   = dpp_xor3(mine);         // unit (base8^24)+ u
        const float* wr0 = enc_w2 + (base8 + u) * NH + base8;
        const float* wr1 = enc_w2 + ((base8 ^ 8) + u) * NH + base8;
        const float* wr2 = enc_w2 + ((base8 ^ 16) + u) * NH + base8;
        const float* wr3 = enc_w2 + ((base8 ^ 24) + u) * NH + base8;
        float4 a0 = *(const float4*)(wr0), a1 = *(const float4*)(wr0 + 4);
        float4 b0 = *(const float4*)(wr1), b1 = *(const float4*)(wr1 + 4);
        float4 c0 = *(const float4*)(wr2), c1 = *(const float4*)(wr2 + 4);
        float4 d0 = *(const float4*)(wr3), d1 = *(const float4*)(wr3 + 4);
        acc[0] = fmaf(mine, a0.x, fmaf(o1, b0.x, fmaf(o2, c0.x, fmaf(o3, d0.x, acc[0]))));
        acc[1] = fmaf(mine, a0.y, fmaf(o1, b0.y, fmaf(o2, c0.y, fmaf(o3, d0.y, acc[1]))));
        acc[2] = fmaf(mine, a0.z, fmaf(o1, b0.z, fmaf(o2, c0.z, fmaf(o3, d0.z, acc[2]))));
        acc[3] = fmaf(mine, a0.w, fmaf(o1, b0.w, fmaf(o2, c0.w, fmaf(o3, d0.w, acc[3]))));
        acc[4] = fmaf(mine, a1.x, fmaf(o1, b1.x, fmaf(o2, c1.x, fmaf(o3, d1.x, acc[4]))));
        acc[5] = fmaf(mine, a1.y, fmaf(o1, b1.y, fmaf(o2, c1.y, fmaf(o3, d1.y, acc[5]))));
        acc[6] = fmaf(mine, a1.z, fmaf(o1, b1.z, fmaf(o2, c1.z, fmaf(o3, d1.z, acc[6]))));
        acc[7] = fmaf(mine, a1.w, fmaf(o1, b1.w, fmaf(o2, c1.w, fmaf(o3, d1.w, acc[7]))));
    }
    // z0 = gelu(acc) @ w3 + b3, 2-stage reduce -> replicated in all 4 lanes
    f2 z[3];
    {
        float zp[NS] = {0.f, 0.f, 0.f, 0.f, 0.f, 0.f};
        #pragma unroll 1
        for (int u = 0; u < 8; ++u) {
            float gm = gelu_exact(acc[u]);
            const float2* wp = (const float2*)(enc_w3 + (base8 + u) * NS);
            float2 w0 = wp[0], w1 = wp[1], w2 = wp[2];
            zp[0] = fmaf(gm, w0.x, zp[0]); zp[1] = fmaf(gm, w0.y, zp[1]);
            zp[2] = fmaf(gm, w1.x, zp[2]); zp[3] = fmaf(gm, w1.y, zp[3]);
            zp[4] = fmaf(gm, w2.x, zp[4]); zp[5] = fmaf(gm, w2.y, zp[5]);
        }
        #pragma unroll
        for (int s = 0; s < 3; ++s) {
            z[s].x = qsum4(zp[2 * s])     + enc_b3[2 * s];
            z[s].y = qsum4(zp[2 * s + 1]) + enc_b3[2 * s + 1];
        }
    }

    auto deriv = [&](const f2 (&zz)[3], f2 (&d)[3]) {
        // a'[p] = C*(b1 + sum_i z_i w1[i][p]) — first fma inits from b1p (no movs)
        f2 a[2];
        #pragma unroll
        for (int p = 0; p < 2; ++p) {
            PK_FMA_LO_I(a[p], zz[0], w1p[0][p], b1p[p]);
            PK_FMA_HI (a[p], zz[0], w1p[1][p]);
        }
        #pragma unroll
        for (int s = 1; s < 3; ++s) {
            #pragma unroll
            for (int p = 0; p < 2; ++p) {
                PK_FMA_LO(a[p], zz[s], w1p[2 * s][p]);
                PK_FMA_HI(a[p], zz[s], w1p[2 * s + 1][p]);
            }
        }
        // rc = 1/(exp2(a')+1)   (y = 1-2rc folded into w2p/hb2p)
        f2 rc[2];
        #pragma unroll
        for (int p = 0; p < 2; ++p) {
            f2 e; e.x = __builtin_amdgcn_exp2f(a[p].x); e.y = __builtin_amdgcn_exp2f(a[p].y);
            f2 r = e + bc2(1.0f);
            rc[p].x = __builtin_amdgcn_rcpf(r.x); rc[p].y = __builtin_amdgcn_rcpf(r.y);
        }
        // pd[s] = hb2p + sum_{local j} rc_j * w2p[j]  — first fma inits from hb2p
        f2 pd[3];
        #pragma unroll
        for (int s = 0; s < 3; ++s) {
            PK_FMA_LO_I(pd[s], rc[0], w2p[0][s], hb2p[s]);
            PK_FMA_HI (pd[s], rc[0], w2p[1][s]);
            PK_FMA_LO (pd[s], rc[1], w2p[2][s]);
            PK_FMA_HI (pd[s], rc[1], w2p[3][s]);
        }
        // 2-stage cross-lane reduce + packed linear assembly:
        //   t = (zz.y*1 + pd.x, zz.x*(-om2) + pd.y); d = (t.x, zz.y*(-2g)+t.y)
        #pragma unroll
        for (int s = 0; s < 3; ++s) {
            f2 o;
            o.x = dpp_xor1(pd[s].x); o.y = dpp_xor1(pd[s].y);
            pd[s] += o;
            o.x = dpp_xor2(pd[s].x); o.y = dpp_xor2(pd[s].y);
            pd[s] += o;
            f2 t;
            PK_FMA_SWAP_I(t, zz[s], c1p[s], pd[s]);
            d[s] = fma2(zz[s], c2p[s], t);
        }
    };

    // ================= t = 0 outputs =================
    float amp[NK];
    {
        float eh = addc;
        #pragma unroll
        for (int k = 0; k < NK; ++k) {
            float xx = z[k].x;
            amp[k] = xx * xx;
            eh = fmaf(xx, dw[k], eh);
        }
        float* tp = out_tr + (size_t)b * NS;
        if (sub == 3) {
            out_eh[(size_t)b * NT] = eh;
        } else {
            f2 zsel = (sub == 0) ? z[0] : ((sub == 1) ? z[1] : z[2]);
            float2 sv = {zsel.x, zsel.y};
            *(float2*)(tp + 2 * sub) = sv;
        }
    }

    // ================= integrate =================
    float te_prev = t_eval[0];
    #pragma unroll 1
    for (int t = 1; t < NT; ++t) {
        const float te  = t_eval[t];
        const float dt  = te - te_prev;
        te_prev = te;
        const float hh  = dt * (1.0f / NSUB);
        const float hh2 = 0.5f * hh;
        const float hh6 = hh * (1.0f / 6.0f);
        f2 hh2p = bc2(hh2), hhp = bc2(hh), hh6p = bc2(hh6);
        #pragma unroll 1
        for (int ss = 0; ss < NSUB; ++ss) {
            f2 d[3], zt[3], zs[3];
            deriv(z, d);                                        // k1
            #pragma unroll
            for (int s = 0; s < 3; ++s) { zs[s] = d[s]; zt[s] = fma2(hh2p, d[s], z[s]); }
            deriv(zt, d);                                       // k2
            #pragma unroll
            for (int s = 0; s < 3; ++s) { zs[s] = fma2(bc2(2.f), d[s], zs[s]); zt[s] = fma2(hh2p, d[s], z[s]); }
            deriv(zt, d);                                       // k3
            #pragma unroll
            for (int s = 0; s < 3; ++s) { zs[s] = fma2(bc2(2.f), d[s], zs[s]); zt[s] = fma2(hhp, d[s], z[s]); }
            deriv(zt, d);                                       // k4
            #pragma unroll
            for (int s = 0; s < 3; ++s) z[s] = fma2(hh6p, zs[s] + d[s], z[s]);
        }
        float eh = addc;
        #pragma unroll
        for (int k = 0; k < NK; ++k) {
            float xx = z[k].x;
            amp[k] = fmaf(xx, xx, amp[k]);
            eh = fmaf(xx, dw[k], eh);
        }
        float* tp = out_tr + ((size_t)t * NB + b) * NS;
        if (sub == 3) {
            out_eh[(size_t)b * NT + t] = eh;
        } else {
            f2 zsel = (sub == 0) ? z[0] : ((sub == 1) ? z[1] : z[2]);
            float2 sv = {zsel.x, zsel.y};
            *(float2*)(tp + 2 * sub) = sv;
        }
    }

    if (sub < 3) {
        float av = (sub == 0) ? amp[0] : ((sub == 1) ? amp[1] : amp[2]);
        out_amp[(size_t)b * NK + sub] = sqrtf(av * (1.0f / NT));
    }
}

extern "C" void kernel_launch(void* const* d_in, const int* in_sizes, int n_in,
                              void* d_out, int out_size, void* d_ws, size_t ws_size,
                              hipStream_t stream) {
    pinod_kernel<<<(NB * 4) / 256, 256, 0, stream>>>(
        (const float*)d_in[0],  (const float*)d_in[1],  (const float*)d_in[2],
        (const float*)d_in[3],  (const float*)d_in[4],  (const float*)d_in[5],
        (const float*)d_in[6],  (const float*)d_in[7],  (const float*)d_in[8],
        (const float*)d_in[9],  (const float*)d_in[10], (const float*)d_in[11],
        (const float*)d_in[12], (const float*)d_in[13], (const float*)d_in[14],
        (const float*)d_in[15], (const float*)d_in[16], (const float*)d_in[17],
        (const float*)d_in[18], (float*)d_out);
}